// Round 2
// baseline (532.024 us; speedup 1.0000x reference)
//
#include <hip/hip_runtime.h>
#include <cstdint>
#include <cstddef>

#define FEATURE_IN 4096
#define FEATURE_OUT 4096
#define RNK 16

typedef __bf16 bf16x8_t __attribute__((ext_vector_type(8)));
typedef __bf16 bf16x4_t __attribute__((ext_vector_type(4)));
typedef float f32x4_t __attribute__((ext_vector_type(4)));

// ===================== convert_x: x fp32 -> bf16, grid-stride =====================
// 2048 blocks x 256 thr; 8.39M float4s = 16 chunks of 524288.  Every load/store
// instruction is unit-stride coalesced (16B/lane loads, 8B/lane stores); 16
// independent chunks give deep ILP.  Was: 16384 micro-blocks (12 KB each) inside a
// branchy mega-kernel -> suspected dispatch-granularity bound (~1.2 TB/s effective).
#define CVT_BLOCKS 2048
#define CVT_TPB 256
#define CVT_THREADS (CVT_BLOCKS * CVT_TPB)          // 524288
#define CVT_CHUNKS 16                               // 8388608 / 524288

__global__ __launch_bounds__(CVT_TPB) void convert_x(const float* __restrict__ x,
                                                     uint16_t* __restrict__ xb) {
    const int tg = blockIdx.x * CVT_TPB + threadIdx.x;
    const float4* xp = (const float4*)x;
    bf16x4_t* op = (bf16x4_t*)xb;
#pragma unroll
    for (int i = 0; i < CVT_CHUNKS; ++i) {
        const int idx = i * CVT_THREADS + tg;
        float4 v = xp[idx];
        bf16x4_t o;
        o[0] = (__bf16)v.x; o[1] = (__bf16)v.y; o[2] = (__bf16)v.z; o[3] = (__bf16)v.w;
        op[idx] = o;
    }
}

// ========== fuse_w: Wf[n,k] = bf16(W[n,k] + 2*sum_r A[k,r]*B[r,n]) ================
#define FW_KB 128
#define FW_NB 32
#define NFUSE 4096            // (K/FW_KB)*(N/FW_NB) = 32*128

__global__ __launch_bounds__(256) void fuse_w(const float* __restrict__ w,
                                              const float* __restrict__ la,
                                              const float* __restrict__ lb,
                                              uint16_t* __restrict__ wf) {
    __shared__ float las[FW_KB * RNK];     // [k][r], 8 KB
    __shared__ float lbs[RNK * FW_NB];     // [r][n], 2 KB

    const int tid = threadIdx.x;
    const int bid = blockIdx.x;
    const int kb = (bid & 31) * FW_KB;
    const int nb = (bid >> 5) * FW_NB;

    {
        const float4* src = (const float4*)(la + (size_t)kb * RNK);
        float4* dst = (float4*)las;
        dst[tid] = src[tid];
        dst[tid + 256] = src[tid + 256];
    }
#pragma unroll
    for (int f = tid; f < RNK * FW_NB; f += 256) {
        int r = f >> 5;
        int nl = f & 31;
        lbs[r * FW_NB + nl] = lb[(size_t)r * FEATURE_OUT + nb + nl];
    }
    __syncthreads();

    const int nl = tid >> 3;    // 0..31
    const int kq = tid & 7;     // 0..7, each covers 16 k

    f32x4_t bcol[4];
#pragma unroll
    for (int r4 = 0; r4 < 4; ++r4) {
        f32x4_t v;
#pragma unroll
        for (int j = 0; j < 4; ++j) v[j] = lbs[(r4 * 4 + j) * FW_NB + nl];
        bcol[r4] = v;
    }

    const f32x4_t* las4 = (const f32x4_t*)las;   // index k*4 + r4
    const float* wrow = w + (size_t)(nb + nl) * FEATURE_IN + kb + kq * 16;
    uint16_t* wfrow = wf + (size_t)(nb + nl) * FEATURE_IN + kb + kq * 16;

#pragma unroll
    for (int h = 0; h < 2; ++h) {          // two groups of 8 k
        float4 wv0 = ((const float4*)wrow)[h * 2 + 0];
        float4 wv1 = ((const float4*)wrow)[h * 2 + 1];
        float wfv[8] = {wv0.x, wv0.y, wv0.z, wv0.w, wv1.x, wv1.y, wv1.z, wv1.w};
        bf16x8_t o;
#pragma unroll
        for (int j = 0; j < 8; ++j) {
            const int k = kq * 16 + h * 8 + j;
            float s = 0.f;
#pragma unroll
            for (int rr = 0; rr < 4; ++rr) {
                const int r4 = (rr + kq) & 3;
                f32x4_t av = las4[k * 4 + r4];
                f32x4_t bv = bcol[r4];
                s += av[0] * bv[0] + av[1] * bv[1] + av[2] * bv[2] + av[3] * bv[3];
            }
            o[j] = (__bf16)(wfv[j] + 2.f * s);
        }
        ((bf16x8_t*)wfrow)[h] = o;
    }
}

// ======================= GEMM: 256x256 tile, 8-phase schedule =======================
// (FROZEN from round 1 — clean A/B vs prep changes.)
// C[M,N] = Xb[M,K] * Wf[N,K]^T + bias.  8 waves (2M x 4N), BK=64, double-buffered
// 128 KiB LDS.  Counted vmcnt(4) twice per K-tile, never 0 in main loop.
// LDS chunk placement row*64 + (((row>>1)+q)&3)*16 -> measured SQ_LDS_BANK_CONFLICT=0.
#define BM 256
#define BN 256
#define BK 64
#define NT (FEATURE_IN / BK)   // 64 K-tiles

#define ABASE(P, KS) ((P) * 65536 + (KS) * 16384)
#define BBASE(P, KS) ((P) * 65536 + 32768 + (KS) * 16384)

#define READ_A(G, P, KS) do { _Pragma("unroll")                                          \
    for (int _mi = 0; _mi < 4; ++_mi)                                                    \
        a[_mi] = *(const bf16x8_t*)(lds + ABASE(P, KS) + aoff[(G) * 4 + _mi]); } while (0)

#define READ_B(P, KS) do { _Pragma("unroll")                                             \
    for (int _ni = 0; _ni < 4; ++_ni)                                                    \
        b[_ni] = *(const bf16x8_t*)(lds + BBASE(P, KS) + boff[_ni]); } while (0)

#define MFMA_G(G) do { _Pragma("unroll")                                                 \
    for (int _mi = 0; _mi < 4; ++_mi) { _Pragma("unroll")                                \
        for (int _ni = 0; _ni < 4; ++_ni)                                                \
            acc[(G) * 4 + _mi][_ni] = __builtin_amdgcn_mfma_f32_16x16x32_bf16(           \
                a[_mi], b[_ni], acc[(G) * 4 + _mi][_ni], 0, 0, 0); } } while (0)

#define STAGE_A(PN, KS) do {                                                             \
    __builtin_amdgcn_global_load_lds(                                                    \
        (const __attribute__((address_space(1))) void*)(pA0 + (KS) * 32),                \
        (__attribute__((address_space(3))) void*)(lds + ABASE(PN, KS) + wv * 1024),      \
        16, 0, 0);                                                                       \
    __builtin_amdgcn_global_load_lds(                                                    \
        (const __attribute__((address_space(1))) void*)(pA1 + (KS) * 32),                \
        (__attribute__((address_space(3))) void*)(lds + ABASE(PN, KS) + 8192 + wv * 1024),\
        16, 0, 0); } while (0)

#define STAGE_B(PN, KS) do {                                                             \
    __builtin_amdgcn_global_load_lds(                                                    \
        (const __attribute__((address_space(1))) void*)(pB0 + (KS) * 32),                \
        (__attribute__((address_space(3))) void*)(lds + BBASE(PN, KS) + wv * 1024),      \
        16, 0, 0);                                                                       \
    __builtin_amdgcn_global_load_lds(                                                    \
        (const __attribute__((address_space(1))) void*)(pB1 + (KS) * 32),                \
        (__attribute__((address_space(3))) void*)(lds + BBASE(PN, KS) + 8192 + wv * 1024),\
        16, 0, 0); } while (0)

#define PBAR() __builtin_amdgcn_s_barrier()
#define PRIO1 __builtin_amdgcn_s_setprio(1)
#define PRIO0 __builtin_amdgcn_s_setprio(0)
#define VMCNT(n) asm volatile("s_waitcnt vmcnt(" #n ")" ::: "memory")

#define TILE_BODY(P, PN)                                                                 \
    /* phase A */                                                                        \
    READ_A(0, P, 0); READ_B(P, 0);                                                       \
    STAGE_A(PN, 0);                                                                      \
    PBAR();                                                                              \
    PRIO1; MFMA_G(0); PRIO0;                                                             \
    PBAR();                                                                              \
    /* phase B */                                                                        \
    READ_A(1, P, 0);                                                                     \
    STAGE_B(PN, 0);                                                                      \
    PBAR();                                                                              \
    PRIO1; MFMA_G(1); PRIO0;                                                             \
    VMCNT(4);                                                                            \
    PBAR();                                                                              \
    /* phase C */                                                                        \
    READ_A(0, P, 1); READ_B(P, 1);                                                       \
    STAGE_A(PN, 1);                                                                      \
    PBAR();                                                                              \
    PRIO1; MFMA_G(0); PRIO0;                                                             \
    PBAR();                                                                              \
    /* phase D */                                                                        \
    READ_A(1, P, 1);                                                                     \
    STAGE_B(PN, 1);                                                                      \
    PBAR();                                                                              \
    PRIO1; MFMA_G(1); PRIO0;                                                             \
    VMCNT(4);                                                                            \
    PBAR();                                                                              \
    pA0 += BK; pA1 += BK; pB0 += BK; pB1 += BK;

__global__ __launch_bounds__(512, 2) void gemm256(const uint16_t* __restrict__ Au,
                                                  const uint16_t* __restrict__ Bu,
                                                  const float* __restrict__ bias,
                                                  float* __restrict__ C,
                                                  int M, int N, int K) {
    __shared__ __align__(16) char lds[131072];   // 2 bufs x (A 32K | B 32K)

    const __bf16* A = (const __bf16*)Au;
    const __bf16* B = (const __bf16*)Bu;

    const int tid  = threadIdx.x;
    const int wv   = tid >> 6;          // 0..7
    const int lane = tid & 63;
    const int waveM = wv >> 2;          // 0..1
    const int waveN = wv & 3;           // 0..3
    const int l15 = lane & 15;
    const int q   = lane >> 4;          // fragment k-chunk 0..3

    // T1: bijective XCD-chunk swizzle (nwg=512, 512%8==0)
    const int nbx = N / BN;
    const int nwg = nbx * (M / BM);
    const int bidlin = blockIdx.y * nbx + blockIdx.x;
    const int swz = (bidlin & 7) * (nwg >> 3) + (bidlin >> 3);
    const int by = swz / nbx;
    const int bx = swz - by * nbx;
    const int m0 = by * BM;
    const int n0 = bx * BN;

    // ---- per-thread staging source (chunk c = j*512+tid -> row c>>2, slot c&3) ----
    const int srow = tid >> 2;                       // 0..127 (load1: +128)
    const int sq   = ((tid & 3) - (srow >> 1)) & 3;  // logical chunk stored at this slot
    const __bf16* pA0 = A + (size_t)(m0 + srow) * K + sq * 8;
    const __bf16* pA1 = pA0 + (size_t)128 * K;
    const __bf16* pB0 = B + (size_t)(n0 + srow) * K + sq * 8;
    const __bf16* pB1 = pB0 + (size_t)128 * K;

    // ---- per-thread fragment LDS byte offsets (within a k-half block) ----
    int aoff[8], boff[4];
#pragma unroll
    for (int mi = 0; mi < 8; ++mi) {
        int row = waveM * 128 + mi * 16 + l15;
        aoff[mi] = row * 64 + (((row >> 1) + q) & 3) * 16;
    }
#pragma unroll
    for (int ni = 0; ni < 4; ++ni) {
        int row = waveN * 64 + ni * 16 + l15;
        boff[ni] = row * 64 + (((row >> 1) + q) & 3) * 16;
    }

    f32x4_t acc[8][4];
#pragma unroll
    for (int mi = 0; mi < 8; ++mi)
#pragma unroll
        for (int ni = 0; ni < 4; ++ni)
            acc[mi][ni] = (f32x4_t)0.f;

    bf16x8_t a[4], b[4];

    // ---- prologue: stage tile 0 into buf0, keep its k-half1 pair in flight ----
    STAGE_A(0, 0); STAGE_B(0, 0); STAGE_A(0, 1); STAGE_B(0, 1);
    pA0 += BK; pA1 += BK; pB0 += BK; pB1 += BK;
    VMCNT(4);
    PBAR();

    // ---- main loop: tiles 0..61 (staging 1..62) ----
#pragma unroll 1
    for (int i = 0; i < (NT - 2) / 2; ++i) {
        TILE_BODY(0, 1)
        TILE_BODY(1, 0)
    }
    // tile 62 (buf0), stages tile 63 into buf1
    TILE_BODY(0, 1)

    // ---- epilogue tile 63 (buf1), no staging; drain remaining loads ----
    READ_A(0, 1, 0); READ_B(1, 0);
    PRIO1; MFMA_G(0); PRIO0;
    READ_A(1, 1, 0);
    PRIO1; MFMA_G(1); PRIO0;
    VMCNT(0);
    PBAR();
    READ_A(0, 1, 1); READ_B(1, 1);
    PRIO1; MFMA_G(0); PRIO0;
    READ_A(1, 1, 1);
    PRIO1; MFMA_G(1); PRIO0;

    // ---- C write: D layout col=lane&15, row=q*4+j ----
#pragma unroll
    for (int ni = 0; ni < 4; ++ni) {
        const int col = n0 + waveN * 64 + ni * 16 + l15;
        const float bv = bias[col];
#pragma unroll
        for (int mi = 0; mi < 8; ++mi) {
            const int row = m0 + waveM * 128 + mi * 16 + q * 4;
            float* op = C + (size_t)row * N + col;
#pragma unroll
            for (int j = 0; j < 4; ++j)
                op[(size_t)j * N] = acc[mi][ni][j] + bv;
        }
    }
}

extern "C" void kernel_launch(void* const* d_in, const int* in_sizes, int n_in,
                              void* d_out, int out_size, void* d_ws, size_t ws_size,
                              hipStream_t stream) {
    const float* x  = (const float*)d_in[0];   // [4,2048,4096]
    const float* w  = (const float*)d_in[1];   // [4096,4096]  (out,in)
    const float* b  = (const float*)d_in[2];   // [4096]
    const float* la = (const float*)d_in[3];   // [4096,16]
    const float* lb = (const float*)d_in[4];   // [16,4096]
    float* out = (float*)d_out;

    const int M = in_sizes[0] / FEATURE_IN;    // 8192
    const int K = FEATURE_IN;
    const int N = FEATURE_OUT;

    uint16_t* xb = (uint16_t*)d_ws;                                  // M*K bf16 = 64 MiB
    uint16_t* wf = (uint16_t*)((char*)d_ws + (size_t)M * K * 2);     // N*K bf16 = 32 MiB

    // 1) x -> bf16 (grid-stride, 2048 blocks)
    convert_x<<<CVT_BLOCKS, CVT_TPB, 0, stream>>>(x, xb);

    // 2) LoRA-folded W -> bf16
    fuse_w<<<NFUSE, 256, 0, stream>>>(w, la, lb, wf);

    // 3) GEMM + bias, 256x256 8-phase
    {
        dim3 grid(N / BN, M / BM);   // (16, 32)
        gemm256<<<grid, 512, 0, stream>>>(xb, wf, b, out, M, N, K);
    }
}

// Round 3
// 513.609 us; speedup vs baseline: 1.0359x; 1.0359x over previous
//
#include <hip/hip_runtime.h>
#include <cstdint>
#include <cstddef>

#define FEATURE_IN 4096
#define FEATURE_OUT 4096
#define RNK 16

typedef __bf16 bf16x8_t __attribute__((ext_vector_type(8)));
typedef __bf16 bf16x4_t __attribute__((ext_vector_type(4)));
typedef float f32x4_t __attribute__((ext_vector_type(4)));

// ================= prep_all: one dispatch, two roles =================
// blocks [0, NFUSE)          : Wf[n,k] = bf16(W[n,k] + 2*sum_r A[k,r]*B[r,n])
// blocks [NFUSE, NFUSE+NCVTB): x fp32 -> bf16 (grid-stride, coalesced)
// Merged into ONE dispatch so it becomes the longest dispatch -> its counters
// (hbm_gbps / VALUBusy / Occupancy) become visible in the top-5 next round.
#define FW_KB 128
#define FW_NB 32
#define NFUSE 4096            // (K/FW_KB)*(N/FW_NB) = 32*128
#define NCVTB 2048
#define CVT_THREADS (NCVTB * 256)                   // 524288
#define CVT_CHUNKS 16                               // 8388608 float4s total

__global__ __launch_bounds__(256) void prep_all(const float* __restrict__ x,
                                                uint16_t* __restrict__ xb,
                                                const float* __restrict__ w,
                                                const float* __restrict__ la,
                                                const float* __restrict__ lb,
                                                uint16_t* __restrict__ wf) {
    __shared__ float las[FW_KB * RNK];     // [k][r], 8 KB
    __shared__ float lbs[RNK * FW_NB];     // [r][n], 2 KB

    const int tid = threadIdx.x;

    if (blockIdx.x >= NFUSE) {
        // ---- convert role ----
        const int tg = (blockIdx.x - NFUSE) * 256 + tid;
        const float4* xp = (const float4*)x;
        bf16x4_t* op = (bf16x4_t*)xb;
#pragma unroll
        for (int i = 0; i < CVT_CHUNKS; ++i) {
            const int idx = i * CVT_THREADS + tg;
            float4 v = xp[idx];
            bf16x4_t o;
            o[0] = (__bf16)v.x; o[1] = (__bf16)v.y; o[2] = (__bf16)v.z; o[3] = (__bf16)v.w;
            op[idx] = o;
        }
        return;
    }

    // ---- fuse role ----
    const int bid = blockIdx.x;
    const int kb = (bid & 31) * FW_KB;
    const int nb = (bid >> 5) * FW_NB;

    {
        const float4* src = (const float4*)(la + (size_t)kb * RNK);
        float4* dst = (float4*)las;
        dst[tid] = src[tid];
        dst[tid + 256] = src[tid + 256];
    }
#pragma unroll
    for (int f = tid; f < RNK * FW_NB; f += 256) {
        int r = f >> 5;
        int nl = f & 31;
        lbs[r * FW_NB + nl] = lb[(size_t)r * FEATURE_OUT + nb + nl];
    }
    __syncthreads();

    const int nl = tid >> 3;    // 0..31
    const int kq = tid & 7;     // 0..7, each covers 16 k

    f32x4_t bcol[4];
#pragma unroll
    for (int r4 = 0; r4 < 4; ++r4) {
        f32x4_t v;
#pragma unroll
        for (int j = 0; j < 4; ++j) v[j] = lbs[(r4 * 4 + j) * FW_NB + nl];
        bcol[r4] = v;
    }

    const f32x4_t* las4 = (const f32x4_t*)las;   // index k*4 + r4
    const float* wrow = w + (size_t)(nb + nl) * FEATURE_IN + kb + kq * 16;
    uint16_t* wfrow = wf + (size_t)(nb + nl) * FEATURE_IN + kb + kq * 16;

#pragma unroll
    for (int h = 0; h < 2; ++h) {          // two groups of 8 k
        float4 wv0 = ((const float4*)wrow)[h * 2 + 0];
        float4 wv1 = ((const float4*)wrow)[h * 2 + 1];
        float wfv[8] = {wv0.x, wv0.y, wv0.z, wv0.w, wv1.x, wv1.y, wv1.z, wv1.w};
        bf16x8_t o;
#pragma unroll
        for (int j = 0; j < 8; ++j) {
            const int k = kq * 16 + h * 8 + j;
            float s = 0.f;
#pragma unroll
            for (int rr = 0; rr < 4; ++rr) {
                const int r4 = (rr + kq) & 3;
                f32x4_t av = las4[k * 4 + r4];
                f32x4_t bv = bcol[r4];
                s += av[0] * bv[0] + av[1] * bv[1] + av[2] * bv[2] + av[3] * bv[3];
            }
            o[j] = (__bf16)(wfv[j] + 2.f * s);
        }
        ((bf16x8_t*)wfrow)[h] = o;
    }
}

// ============== GEMM: 256x256 tile, BK=32, 4-buffer, stage-3-ahead ==============
// C[M,N] = Xb[M,K] * Wf[N,K]^T + bias.  8 waves (2M x 4N), 4 x 32KB LDS buffers.
// Per K-tile (2 phases of 16 MFMA) we stage tile t+3; ONE counted vmcnt(8)/tile.
// Derivation: old BK=64 dbuf scheme waited on loads issued only ~2 phases (~200cy)
// earlier (< LLC latency) -> 47% MfmaUtil.  4-buffer gives every load a 4-5 phase
// (~500cy) issue->wait distance.  LDS placement row*64 + (((row>>1)+q)&3)*16 is
// 2-way-max on fragment reads (measured SQ_LDS_BANK_CONFLICT == 0).
#define BM 256
#define BN 256
#define BK 32
#define NT (FEATURE_IN / BK)   // 128 K-tiles

#define ABUF(b) ((b) * 32768)
#define BBUF(b) ((b) * 32768 + 16384)

#define READ_A0(b) do { _Pragma("unroll")                                                \
    for (int _mi = 0; _mi < 4; ++_mi)                                                    \
        af[_mi] = *(const bf16x8_t*)(lds + ABUF(b) + aoff[_mi]); } while (0)

#define READ_A1(b) do { _Pragma("unroll")                                                \
    for (int _mi = 0; _mi < 4; ++_mi)                                                    \
        af[_mi] = *(const bf16x8_t*)(lds + ABUF(b) + aoff[4 + _mi]); } while (0)

#define READ_B4(b) do { _Pragma("unroll")                                                \
    for (int _ni = 0; _ni < 4; ++_ni)                                                    \
        bq[_ni] = *(const bf16x8_t*)(lds + BBUF(b) + boff[_ni]); } while (0)

#define MFMA16(G) do { _Pragma("unroll")                                                 \
    for (int _mi = 0; _mi < 4; ++_mi) { _Pragma("unroll")                                \
        for (int _ni = 0; _ni < 4; ++_ni)                                                \
            acc[(G) * 4 + _mi][_ni] = __builtin_amdgcn_mfma_f32_16x16x32_bf16(           \
                af[_mi], bq[_ni], acc[(G) * 4 + _mi][_ni], 0, 0, 0); } } while (0)

#define GLL(SRC, DSTOFF)                                                                 \
    __builtin_amdgcn_global_load_lds(                                                    \
        (const __attribute__((address_space(1))) void*)(SRC),                            \
        (__attribute__((address_space(3))) void*)(lds + (DSTOFF) + wv * 1024), 16, 0, 0)

#define STAGE_A(b) do { GLL(pA0, ABUF(b)); GLL(pA1, ABUF(b) + 8192); } while (0)
#define STAGE_B(b) do { GLL(pB0, BBUF(b)); GLL(pB1, BBUF(b) + 8192); } while (0)

#define PBAR() __builtin_amdgcn_s_barrier()
#define PRIO1 __builtin_amdgcn_s_setprio(1)
#define PRIO0 __builtin_amdgcn_s_setprio(0)
#define VMCNT(n) asm volatile("s_waitcnt vmcnt(" #n ")" ::: "memory")

// Body for tile in buffer CUR, staging tile+3 into buffer NXT.
// End-of-tile VMCNT(8): outstanding = 12 (3 staged tiles x 4 loads); retires the
// 4 loads of tile+1 (issued 2 tiles = 4 phases earlier) before the barrier that
// publishes them to next body's ds_reads.
#define TILE_BODY(CUR, NXT)                                                              \
    READ_A0(CUR); READ_B4(CUR);                                                          \
    STAGE_A(NXT);                                                                        \
    PBAR();                                                                              \
    PRIO1; MFMA16(0); PRIO0;                                                             \
    PBAR();                                                                              \
    READ_A1(CUR);                                                                        \
    STAGE_B(NXT);                                                                        \
    PBAR();                                                                              \
    PRIO1; MFMA16(1); PRIO0;                                                             \
    VMCNT(8);                                                                            \
    PBAR();                                                                              \
    pA0 += BK; pA1 += BK; pB0 += BK; pB1 += BK;

#define DRAIN_BODY(CUR, NWAIT)                                                           \
    READ_A0(CUR); READ_B4(CUR);                                                          \
    PRIO1; MFMA16(0); PRIO0;                                                             \
    READ_A1(CUR);                                                                        \
    PRIO1; MFMA16(1); PRIO0;                                                             \
    VMCNT(NWAIT);                                                                        \
    PBAR();

__global__ __launch_bounds__(512, 2) void gemm256(const uint16_t* __restrict__ Au,
                                                  const uint16_t* __restrict__ Bu,
                                                  const float* __restrict__ bias,
                                                  float* __restrict__ C,
                                                  int M, int N, int K) {
    __shared__ __align__(16) char lds[131072];   // 4 bufs x (A 16K | B 16K)

    const __bf16* A = (const __bf16*)Au;
    const __bf16* B = (const __bf16*)Bu;

    const int tid  = threadIdx.x;
    const int wv   = tid >> 6;          // 0..7
    const int lane = tid & 63;
    const int waveM = wv >> 2;          // 0..1
    const int waveN = wv & 3;           // 0..3
    const int l15 = lane & 15;
    const int q   = lane >> 4;          // fragment k-chunk 0..3

    // T1: bijective XCD-chunk swizzle (nwg=512, 512%8==0)
    const int nbx = N / BN;
    const int nwg = nbx * (M / BM);
    const int bidlin = blockIdx.y * nbx + blockIdx.x;
    const int swz = (bidlin & 7) * (nwg >> 3) + (bidlin >> 3);
    const int by = swz / nbx;
    const int bx = swz - by * nbx;
    const int m0 = by * BM;
    const int n0 = bx * BN;

    // ---- per-thread staging source (chunk c -> row c>>2, phys slot c&3) ----
    const int srow = tid >> 2;                       // 0..127 (second load: +128)
    const int sq   = ((tid & 3) - (srow >> 1)) & 3;  // logical chunk stored at this slot
    const __bf16* pA0 = A + (size_t)(m0 + srow) * K + sq * 8;
    const __bf16* pA1 = pA0 + (size_t)128 * K;
    const __bf16* pB0 = B + (size_t)(n0 + srow) * K + sq * 8;
    const __bf16* pB1 = pB0 + (size_t)128 * K;

    // ---- per-thread fragment LDS byte offsets (within a 16 KB tile block) ----
    int aoff[8], boff[4];
#pragma unroll
    for (int mi = 0; mi < 8; ++mi) {
        int row = waveM * 128 + mi * 16 + l15;
        aoff[mi] = row * 64 + (((row >> 1) + q) & 3) * 16;
    }
#pragma unroll
    for (int ni = 0; ni < 4; ++ni) {
        int row = waveN * 64 + ni * 16 + l15;
        boff[ni] = row * 64 + (((row >> 1) + q) & 3) * 16;
    }

    f32x4_t acc[8][4];
#pragma unroll
    for (int mi = 0; mi < 8; ++mi)
#pragma unroll
        for (int ni = 0; ni < 4; ++ni)
            acc[mi][ni] = (f32x4_t)0.f;

    bf16x8_t af[4], bq[4];

    // ---- prologue: stage tiles 0,1,2 into bufs 0,1,2 (12 loads in flight) ----
    STAGE_A(0); STAGE_B(0); pA0 += BK; pA1 += BK; pB0 += BK; pB1 += BK;
    STAGE_A(1); STAGE_B(1); pA0 += BK; pA1 += BK; pB0 += BK; pB1 += BK;
    STAGE_A(2); STAGE_B(2); pA0 += BK; pA1 += BK; pB0 += BK; pB1 += BK;
    VMCNT(8);   // retire tile 0's 4 loads
    PBAR();

    // ---- main: bodies t=0..123 (stage tiles 3..126) ----
#pragma unroll 1
    for (int i = 0; i < 31; ++i) {
        TILE_BODY(0, 3)
        TILE_BODY(1, 0)
        TILE_BODY(2, 1)
        TILE_BODY(3, 2)
    }
    // t=124 (buf0), stages tile 127 into buf3
    TILE_BODY(0, 3)

    // ---- drain: t=125 (buf1), t=126 (buf2), t=127 (buf3) ----
    DRAIN_BODY(1, 4)
    DRAIN_BODY(2, 0)
    READ_A0(3); READ_B4(3);
    PRIO1; MFMA16(0); PRIO0;
    READ_A1(3);
    PRIO1; MFMA16(1); PRIO0;

    // ---- C write: D layout col=lane&15, row=q*4+j ----
#pragma unroll
    for (int ni = 0; ni < 4; ++ni) {
        const int col = n0 + waveN * 64 + ni * 16 + l15;
        const float bv = bias[col];
#pragma unroll
        for (int mi = 0; mi < 8; ++mi) {
            const int row = m0 + waveM * 128 + mi * 16 + q * 4;
            float* op = C + (size_t)row * N + col;
#pragma unroll
            for (int j = 0; j < 4; ++j)
                op[(size_t)j * N] = acc[mi][ni][j] + bv;
        }
    }
}

extern "C" void kernel_launch(void* const* d_in, const int* in_sizes, int n_in,
                              void* d_out, int out_size, void* d_ws, size_t ws_size,
                              hipStream_t stream) {
    const float* x  = (const float*)d_in[0];   // [4,2048,4096]
    const float* w  = (const float*)d_in[1];   // [4096,4096]  (out,in)
    const float* b  = (const float*)d_in[2];   // [4096]
    const float* la = (const float*)d_in[3];   // [4096,16]
    const float* lb = (const float*)d_in[4];   // [16,4096]
    float* out = (float*)d_out;

    const int M = in_sizes[0] / FEATURE_IN;    // 8192
    const int K = FEATURE_IN;
    const int N = FEATURE_OUT;

    uint16_t* xb = (uint16_t*)d_ws;                                  // M*K bf16 = 64 MiB
    uint16_t* wf = (uint16_t*)((char*)d_ws + (size_t)M * K * 2);     // N*K bf16 = 32 MiB

    // 1) prep: x->bf16 + LoRA-folded W->bf16 (single dispatch, both roles)
    prep_all<<<NFUSE + NCVTB, 256, 0, stream>>>(x, xb, w, la, lb, wf);

    // 2) GEMM + bias, 256x256, BK=32, 4-buffer pipeline
    {
        dim3 grid(N / BN, M / BM);   // (16, 32)
        gemm256<<<grid, 512, 0, stream>>>(xb, wf, b, out, M, N, K);
    }
}

// Round 4
// 508.968 us; speedup vs baseline: 1.0453x; 1.0091x over previous
//
#include <hip/hip_runtime.h>
#include <cstdint>
#include <cstddef>

#define FEATURE_IN 4096
#define FEATURE_OUT 4096
#define RNK 16

typedef __bf16 bf16x8_t __attribute__((ext_vector_type(8)));
typedef __bf16 bf16x4_t __attribute__((ext_vector_type(4)));
typedef float f32x4_t __attribute__((ext_vector_type(4)));

// ================= prep_all: one dispatch, two roles (FROZEN from r3) =================
#define FW_KB 128
#define FW_NB 32
#define NFUSE 4096            // (K/FW_KB)*(N/FW_NB) = 32*128
#define NCVTB 2048
#define CVT_THREADS (NCVTB * 256)                   // 524288
#define CVT_CHUNKS 16                               // 8388608 float4s total

__global__ __launch_bounds__(256) void prep_all(const float* __restrict__ x,
                                                uint16_t* __restrict__ xb,
                                                const float* __restrict__ w,
                                                const float* __restrict__ la,
                                                const float* __restrict__ lb,
                                                uint16_t* __restrict__ wf) {
    __shared__ float las[FW_KB * RNK];     // [k][r], 8 KB
    __shared__ float lbs[RNK * FW_NB];     // [r][n], 2 KB

    const int tid = threadIdx.x;

    if (blockIdx.x >= NFUSE) {
        // ---- convert role ----
        const int tg = (blockIdx.x - NFUSE) * 256 + tid;
        const float4* xp = (const float4*)x;
        bf16x4_t* op = (bf16x4_t*)xb;
#pragma unroll
        for (int i = 0; i < CVT_CHUNKS; ++i) {
            const int idx = i * CVT_THREADS + tg;
            float4 v = xp[idx];
            bf16x4_t o;
            o[0] = (__bf16)v.x; o[1] = (__bf16)v.y; o[2] = (__bf16)v.z; o[3] = (__bf16)v.w;
            op[idx] = o;
        }
        return;
    }

    // ---- fuse role ----
    const int bid = blockIdx.x;
    const int kb = (bid & 31) * FW_KB;
    const int nb = (bid >> 5) * FW_NB;

    {
        const float4* src = (const float4*)(la + (size_t)kb * RNK);
        float4* dst = (float4*)las;
        dst[tid] = src[tid];
        dst[tid + 256] = src[tid + 256];
    }
#pragma unroll
    for (int f = tid; f < RNK * FW_NB; f += 256) {
        int r = f >> 5;
        int nl = f & 31;
        lbs[r * FW_NB + nl] = lb[(size_t)r * FEATURE_OUT + nb + nl];
    }
    __syncthreads();

    const int nl = tid >> 3;    // 0..31
    const int kq = tid & 7;     // 0..7, each covers 16 k

    f32x4_t bcol[4];
#pragma unroll
    for (int r4 = 0; r4 < 4; ++r4) {
        f32x4_t v;
#pragma unroll
        for (int j = 0; j < 4; ++j) v[j] = lbs[(r4 * 4 + j) * FW_NB + nl];
        bcol[r4] = v;
    }

    const f32x4_t* las4 = (const f32x4_t*)las;   // index k*4 + r4
    const float* wrow = w + (size_t)(nb + nl) * FEATURE_IN + kb + kq * 16;
    uint16_t* wfrow = wf + (size_t)(nb + nl) * FEATURE_IN + kb + kq * 16;

#pragma unroll
    for (int h = 0; h < 2; ++h) {          // two groups of 8 k
        float4 wv0 = ((const float4*)wrow)[h * 2 + 0];
        float4 wv1 = ((const float4*)wrow)[h * 2 + 1];
        float wfv[8] = {wv0.x, wv0.y, wv0.z, wv0.w, wv1.x, wv1.y, wv1.z, wv1.w};
        bf16x8_t o;
#pragma unroll
        for (int j = 0; j < 8; ++j) {
            const int k = kq * 16 + h * 8 + j;
            float s = 0.f;
#pragma unroll
            for (int rr = 0; rr < 4; ++rr) {
                const int r4 = (rr + kq) & 3;
                f32x4_t av = las4[k * 4 + r4];
                f32x4_t bv = bcol[r4];
                s += av[0] * bv[0] + av[1] * bv[1] + av[2] * bv[2] + av[3] * bv[3];
            }
            o[j] = (__bf16)(wfv[j] + 2.f * s);
        }
        ((bf16x8_t*)wfrow)[h] = o;
    }
}

// ====== GEMM: 256x256, BK=32, 4-buffer stage-3-ahead, reg-pipelined fragments ======
// r3 post-mortem: per K-tile, MFMA (1242 cyc/CU) and LDS fragment reads (~1150
// cyc/CU) were SERIALIZED by the read->wait->consume-in-same-phase structure ->
// MfmaUtil stuck at 47%.  Fix: issue each phase's ds_reads ONE PHASE EARLY into a
// second register set; MFMA runs on last phase's registers while reads drain.
// sched_barrier(0) pins {reads, stage-issue} above the MFMA block.  Publish point
// (VMCNT(6)+barrier) moves to mid-tile so P1 may prefetch tile t+1's fragments.
// 2 barriers/tile (was 4).  LDS placement unchanged (measured 0 bank conflicts).
#define BM 256
#define BN 256
#define BK 32
#define NT (FEATURE_IN / BK)   // 128 K-tiles

#define ABUF(b) ((b) * 32768)
#define BBUF(b) ((b) * 32768 + 16384)

// MFMA group X: acc rows 0..3 from afx[S]; group Y: acc rows 4..7 from afy.
#define MFMA16X(S) do { _Pragma("unroll")                                                \
    for (int _mi = 0; _mi < 4; ++_mi) { _Pragma("unroll")                                \
        for (int _ni = 0; _ni < 4; ++_ni)                                                \
            acc[_mi][_ni] = __builtin_amdgcn_mfma_f32_16x16x32_bf16(                     \
                afx[S][_mi], bqr[S][_ni], acc[_mi][_ni], 0, 0, 0); } } while (0)

#define MFMA16Y(S) do { _Pragma("unroll")                                                \
    for (int _mi = 0; _mi < 4; ++_mi) { _Pragma("unroll")                                \
        for (int _ni = 0; _ni < 4; ++_ni)                                                \
            acc[4 + _mi][_ni] = __builtin_amdgcn_mfma_f32_16x16x32_bf16(                 \
                afy[_mi], bqr[S][_ni], acc[4 + _mi][_ni], 0, 0, 0); } } while (0)

#define READ_AFY(b) do { _Pragma("unroll")                                               \
    for (int _mi = 0; _mi < 4; ++_mi)                                                    \
        afy[_mi] = *(const bf16x8_t*)(lds + ABUF(b) + aoff[4 + _mi]); } while (0)

#define READ_R0(b, SN) do { _Pragma("unroll")                                            \
    for (int _mi = 0; _mi < 4; ++_mi)                                                    \
        afx[SN][_mi] = *(const bf16x8_t*)(lds + ABUF(b) + aoff[_mi]);                    \
    _Pragma("unroll")                                                                    \
    for (int _ni = 0; _ni < 4; ++_ni)                                                    \
        bqr[SN][_ni] = *(const bf16x8_t*)(lds + BBUF(b) + boff[_ni]); } while (0)

#define GLL(SRC, DSTOFF)                                                                 \
    __builtin_amdgcn_global_load_lds(                                                    \
        (const __attribute__((address_space(1))) void*)(SRC),                            \
        (__attribute__((address_space(3))) void*)(lds + (DSTOFF) + wv * 1024), 16, 0, 0)

#define STAGE_A(b) do { GLL(pA0, ABUF(b)); GLL(pA1, ABUF(b) + 8192); } while (0)
#define STAGE_B(b) do { GLL(pB0, BBUF(b)); GLL(pB1, BBUF(b) + 8192); } while (0)

#define PBAR() __builtin_amdgcn_s_barrier()
#define PRIO1 __builtin_amdgcn_s_setprio(1)
#define PRIO0 __builtin_amdgcn_s_setprio(0)
#define VMCNT(n) asm volatile("s_waitcnt vmcnt(" #n ")" ::: "memory")
#define SCHEDB() __builtin_amdgcn_sched_barrier(0)

// Tile t in buf CUR (parity set S), staging tile t+3 into buf NXT.
// P0: prefetch afy(t) [4 reads] under MFMA-X(t).  Mid: VMCNT(6) retires exactly
// tile t+1's 4 loads (t+2,t+3 stay in flight) + barrier -> buf(t+1) published.
// P1: prefetch R0(t+1) [8 reads] under MFMA-Y(t).  End barrier = WAR fence for
// next tile's STAGE_A into buf(t).
#define TILE_BODY(CUR, NXT, S, SN)                                                       \
    READ_AFY(CUR);                                                                       \
    STAGE_A(NXT);                                                                        \
    SCHEDB();                                                                            \
    PRIO1; MFMA16X(S); PRIO0;                                                            \
    VMCNT(6);                                                                            \
    PBAR();                                                                              \
    READ_R0((CUR + 1) & 3, SN);                                                          \
    STAGE_B(NXT);                                                                        \
    SCHEDB();                                                                            \
    PRIO1; MFMA16Y(S); PRIO0;                                                            \
    PBAR();                                                                              \
    pA0 += BK; pA1 += BK; pB0 += BK; pB1 += BK;

// Tail tile (no staging): NWAIT counted to retire exactly tile t+1's 4 loads.
#define TAIL_BODY(CUR, S, SN, NWAIT)                                                     \
    READ_AFY(CUR);                                                                       \
    SCHEDB();                                                                            \
    PRIO1; MFMA16X(S); PRIO0;                                                            \
    VMCNT(NWAIT);                                                                        \
    PBAR();                                                                              \
    READ_R0((CUR + 1) & 3, SN);                                                          \
    SCHEDB();                                                                            \
    PRIO1; MFMA16Y(S); PRIO0;                                                            \
    PBAR();

__global__ __launch_bounds__(512, 2) void gemm256(const uint16_t* __restrict__ Au,
                                                  const uint16_t* __restrict__ Bu,
                                                  const float* __restrict__ bias,
                                                  float* __restrict__ C,
                                                  int M, int N, int K) {
    __shared__ __align__(16) char lds[131072];   // 4 bufs x (A 16K | B 16K)

    const __bf16* A = (const __bf16*)Au;
    const __bf16* B = (const __bf16*)Bu;

    const int tid  = threadIdx.x;
    const int wv   = tid >> 6;          // 0..7
    const int lane = tid & 63;
    const int waveM = wv >> 2;          // 0..1
    const int waveN = wv & 3;           // 0..3
    const int l15 = lane & 15;
    const int q   = lane >> 4;          // fragment k-chunk 0..3

    // T1: bijective XCD-chunk swizzle (nwg=512, 512%8==0)
    const int nbx = N / BN;
    const int nwg = nbx * (M / BM);
    const int bidlin = blockIdx.y * nbx + blockIdx.x;
    const int swz = (bidlin & 7) * (nwg >> 3) + (bidlin >> 3);
    const int by = swz / nbx;
    const int bx = swz - by * nbx;
    const int m0 = by * BM;
    const int n0 = bx * BN;

    // ---- per-thread staging source (chunk c -> row c>>2, phys slot c&3) ----
    const int srow = tid >> 2;                       // 0..127 (second load: +128)
    const int sq   = ((tid & 3) - (srow >> 1)) & 3;  // logical chunk stored at this slot
    const __bf16* pA0 = A + (size_t)(m0 + srow) * K + sq * 8;
    const __bf16* pA1 = pA0 + (size_t)128 * K;
    const __bf16* pB0 = B + (size_t)(n0 + srow) * K + sq * 8;
    const __bf16* pB1 = pB0 + (size_t)128 * K;

    // ---- per-thread fragment LDS byte offsets (within a 16 KB tile block) ----
    int aoff[8], boff[4];
#pragma unroll
    for (int mi = 0; mi < 8; ++mi) {
        int row = waveM * 128 + mi * 16 + l15;
        aoff[mi] = row * 64 + (((row >> 1) + q) & 3) * 16;
    }
#pragma unroll
    for (int ni = 0; ni < 4; ++ni) {
        int row = waveN * 64 + ni * 16 + l15;
        boff[ni] = row * 64 + (((row >> 1) + q) & 3) * 16;
    }

    f32x4_t acc[8][4];
#pragma unroll
    for (int mi = 0; mi < 8; ++mi)
#pragma unroll
        for (int ni = 0; ni < 4; ++ni)
            acc[mi][ni] = (f32x4_t)0.f;

    // fragment register sets: afx/bqr double-buffered by tile parity, afy single
    bf16x8_t afx[2][4], afy[4], bqr[2][4];

    // ---- prologue: stage tiles 0,1,2 (12 loads/wave); publish buf0; prime R0(0) ----
    STAGE_A(0); STAGE_B(0); pA0 += BK; pA1 += BK; pB0 += BK; pB1 += BK;
    STAGE_A(1); STAGE_B(1); pA0 += BK; pA1 += BK; pB0 += BK; pB1 += BK;
    STAGE_A(2); STAGE_B(2); pA0 += BK; pA1 += BK; pB0 += BK; pB1 += BK;
    VMCNT(8);   // retire tile 0's 4 loads
    PBAR();
    READ_R0(0, 0);   // prime set0 with tile 0's low-half fragments

    // ---- main: t=0..123 (stage tiles 3..126), parity = t&1 ----
#pragma unroll 1
    for (int i = 0; i < 31; ++i) {
        TILE_BODY(0, 3, 0, 1)
        TILE_BODY(1, 0, 1, 0)
        TILE_BODY(2, 1, 0, 1)
        TILE_BODY(3, 2, 1, 0)
    }
    // t=124 (buf0, set0): stages tile 127 into buf3
    TILE_BODY(0, 3, 0, 1)

    // ---- drain: t=125 (buf1,set1), t=126 (buf2,set0) ----
    TAIL_BODY(1, 1, 0, 4)    // VMCNT(4): retires tile 126's pair
    TAIL_BODY(2, 0, 1, 0)    // VMCNT(0): retires tile 127's pair
    // t=127 (buf3, set1)
    READ_AFY(3);
    SCHEDB();
    PRIO1; MFMA16X(1); PRIO0;
    PRIO1; MFMA16Y(1); PRIO0;

    // ---- C write: D layout col=lane&15, row=q*4+j ----
#pragma unroll
    for (int ni = 0; ni < 4; ++ni) {
        const int col = n0 + waveN * 64 + ni * 16 + l15;
        const float bv = bias[col];
#pragma unroll
        for (int mi = 0; mi < 8; ++mi) {
            const int row = m0 + waveM * 128 + mi * 16 + q * 4;
            float* op = C + (size_t)row * N + col;
#pragma unroll
            for (int j = 0; j < 4; ++j)
                op[(size_t)j * N] = acc[mi][ni][j] + bv;
        }
    }
}

extern "C" void kernel_launch(void* const* d_in, const int* in_sizes, int n_in,
                              void* d_out, int out_size, void* d_ws, size_t ws_size,
                              hipStream_t stream) {
    const float* x  = (const float*)d_in[0];   // [4,2048,4096]
    const float* w  = (const float*)d_in[1];   // [4096,4096]  (out,in)
    const float* b  = (const float*)d_in[2];   // [4096]
    const float* la = (const float*)d_in[3];   // [4096,16]
    const float* lb = (const float*)d_in[4];   // [16,4096]
    float* out = (float*)d_out;

    const int M = in_sizes[0] / FEATURE_IN;    // 8192
    const int K = FEATURE_IN;
    const int N = FEATURE_OUT;

    uint16_t* xb = (uint16_t*)d_ws;                                  // M*K bf16 = 64 MiB
    uint16_t* wf = (uint16_t*)((char*)d_ws + (size_t)M * K * 2);     // N*K bf16 = 32 MiB

    // 1) prep: x->bf16 + LoRA-folded W->bf16 (single dispatch, both roles)
    prep_all<<<NFUSE + NCVTB, 256, 0, stream>>>(x, xb, w, la, lb, wf);

    // 2) GEMM + bias, 256x256, BK=32, 4-buffer, reg-pipelined
    {
        dim3 grid(N / BN, M / BM);   // (16, 32)
        gemm256<<<grid, 512, 0, stream>>>(xb, wf, b, out, M, N, K);
    }
}